// Round 1
// baseline (9201.543 us; speedup 1.0000x reference)
//
#include <hip/hip_runtime.h>

#define BB   64
#define TT   512
#define INP  256
#define HID  1024
#define OUTP 256
#define G4   4096
#define KK   1280   // HID + INP

typedef _Float16 half_t;
typedef __attribute__((ext_vector_type(8))) _Float16 half8;
typedef __attribute__((ext_vector_type(4))) float f32x4;

__device__ __forceinline__ float sigf(float x) { return 1.0f / (1.0f + __expf(-x)); }

// ---------------- setup: convert weights/x to fp16, init state ----------------
__global__ void setup_kernel(const float* __restrict__ x, const float* __restrict__ W_ih,
                             const float* __restrict__ W_hh, const float* __restrict__ b_ih,
                             const float* __restrict__ b_hh, const float* __restrict__ W_out,
                             half_t* __restrict__ Wp, half_t* __restrict__ Wo,
                             half_t* __restrict__ x16, float* __restrict__ bsum,
                             half_t* __restrict__ hbuf, float* __restrict__ cbuf) {
  const int stride = gridDim.x * blockDim.x;
  const int i0 = blockIdx.x * blockDim.x + threadIdx.x;
  // Wp = [W_hh | W_ih] as (4096, 1280) row-major fp16
  for (int i = i0; i < G4 * KK; i += stride) {
    int n = i / KK, k = i - n * KK;
    float v = (k < HID) ? W_hh[n * HID + k] : W_ih[n * INP + (k - HID)];
    Wp[i] = (half_t)v;
  }
  for (int i = i0; i < OUTP * HID; i += stride) Wo[i] = (half_t)W_out[i];
  for (int i = i0; i < BB * TT * INP; i += stride) x16[i] = (half_t)x[i];
  for (int i = i0; i < G4; i += stride) bsum[i] = b_ih[i] + b_hh[i];
  for (int i = i0; i < 2 * BB * HID; i += stride) hbuf[i] = (half_t)0.0f;
  for (int i = i0; i < BB * HID; i += stride) cbuf[i] = 0.0f;
}

// ---------------- one timestep ----------------
// blocks 0..127 : gate GEMM + cell update for hidden units [blk*8, blk*8+8)
// blocks 128..135: out[t-1] = h_t @ W_out^T + b_out   (t>=1)
// t ranges 0..512; at t==512 only out-blocks run (epilogue for out[511]).
__global__ __launch_bounds__(256) void lstm_step(
    int t,
    const half_t* __restrict__ Wp,   // (4096, 1280)
    const half_t* __restrict__ Wo,   // (256, 1024)
    const half_t* __restrict__ x16,  // (64, 512, 256)
    const float* __restrict__ bsum,  // (4096)
    const float* __restrict__ b_out, // (256)
    half_t* __restrict__ hbuf,       // 2 x (64, 1024), h_t in hbuf[t&1]
    float* __restrict__ cbuf,        // (64, 1024)
    float* __restrict__ out)         // (64, 512, 256)
{
  const int tid  = threadIdx.x;
  const int wave = tid >> 6;
  const int lane = tid & 63;
  const int l15  = lane & 15;
  const int lhi  = lane >> 4;
  const int kbase = lhi * 8;
  const half_t* __restrict__ hcur = hbuf + (size_t)(t & 1) * (BB * HID);

  if (blockIdx.x < 128) {
    if (t >= TT) return;
    half_t* __restrict__ hnext = hbuf + (size_t)((t + 1) & 1) * (BB * HID);
    const int hu0  = blockIdx.x * 8;
    const int mrow = wave * 16 + l15;          // batch row for A fragments
    const int nl0  = l15;                      // block-local col, tile 0
    const int nl1  = 16 + l15;                 // block-local col, tile 1
    // block-local col -> W' row: gate = nl>>3 in {i,f,g,o}, unit = hu0 + (nl&7)
    const int r0 = ((nl0 >> 3) * HID) + hu0 + (nl0 & 7);
    const int r1 = ((nl1 >> 3) * HID) + hu0 + (nl1 & 7);
    const half_t* __restrict__ bp0 = Wp + (size_t)r0 * KK;
    const half_t* __restrict__ bp1 = Wp + (size_t)r1 * KK;
    const half_t* __restrict__ ah  = hcur + (size_t)mrow * HID;
    const half_t* __restrict__ ax  = x16 + ((size_t)mrow * TT + t) * INP;

    f32x4 acc0 = {0.f, 0.f, 0.f, 0.f}, acc1 = {0.f, 0.f, 0.f, 0.f};
    #pragma unroll 8
    for (int kk = 0; kk < HID; kk += 32) {
      half8 a  = *(const half8*)(ah + kk + kbase);
      half8 b0 = *(const half8*)(bp0 + kk + kbase);
      half8 b1 = *(const half8*)(bp1 + kk + kbase);
      acc0 = __builtin_amdgcn_mfma_f32_16x16x32_f16(a, b0, acc0, 0, 0, 0);
      acc1 = __builtin_amdgcn_mfma_f32_16x16x32_f16(a, b1, acc1, 0, 0, 0);
    }
    #pragma unroll
    for (int kk = 0; kk < INP; kk += 32) {
      half8 a  = *(const half8*)(ax + kk + kbase);
      half8 b0 = *(const half8*)(bp0 + HID + kk + kbase);
      half8 b1 = *(const half8*)(bp1 + HID + kk + kbase);
      acc0 = __builtin_amdgcn_mfma_f32_16x16x32_f16(a, b0, acc0, 0, 0, 0);
      acc1 = __builtin_amdgcn_mfma_f32_16x16x32_f16(a, b1, acc1, 0, 0, 0);
    }
    // C/D layout: elem r of acc holds row (wave*16 + lhi*4 + r), col (l15) of tile
    const float bs0 = bsum[r0], bs1 = bsum[r1];
    float i_or_f[4], g_or_o[4], fsh[4], osh[4];
    #pragma unroll
    for (int r = 0; r < 4; ++r) { i_or_f[r] = acc0[r] + bs0; g_or_o[r] = acc1[r] + bs1; }
    // lanes with l15<8 hold i (tile0) and g (tile1); partner lane l^8 holds f and o
    #pragma unroll
    for (int r = 0; r < 4; ++r) {
      fsh[r] = __shfl_xor(i_or_f[r], 8);
      osh[r] = __shfl_xor(g_or_o[r], 8);
    }
    if (l15 < 8) {
      const int hu = hu0 + l15;
      #pragma unroll
      for (int r = 0; r < 4; ++r) {
        const int b = wave * 16 + lhi * 4 + r;
        float iv = sigf(i_or_f[r]);
        float fv = sigf(fsh[r]);
        float gv = tanhf(g_or_o[r]);
        float ov = sigf(osh[r]);
        float c  = fv * cbuf[b * HID + hu] + iv * gv;
        cbuf[b * HID + hu] = c;
        hnext[b * HID + hu] = (half_t)(ov * tanhf(c));
      }
    }
  } else {
    if (t == 0) return;
    const int ob   = blockIdx.x - 128;
    const int base = ob * 32;
    const int mrow = wave * 16 + l15;
    const int oc0  = base + l15;
    const int oc1  = base + 16 + l15;
    const half_t* __restrict__ bp0 = Wo + (size_t)oc0 * HID;
    const half_t* __restrict__ bp1 = Wo + (size_t)oc1 * HID;
    const half_t* __restrict__ ah  = hcur + (size_t)mrow * HID;
    f32x4 acc0 = {0.f, 0.f, 0.f, 0.f}, acc1 = {0.f, 0.f, 0.f, 0.f};
    #pragma unroll 8
    for (int kk = 0; kk < HID; kk += 32) {
      half8 a  = *(const half8*)(ah + kk + kbase);
      half8 b0 = *(const half8*)(bp0 + kk + kbase);
      half8 b1 = *(const half8*)(bp1 + kk + kbase);
      acc0 = __builtin_amdgcn_mfma_f32_16x16x32_f16(a, b0, acc0, 0, 0, 0);
      acc1 = __builtin_amdgcn_mfma_f32_16x16x32_f16(a, b1, acc1, 0, 0, 0);
    }
    const float bo0 = b_out[oc0], bo1 = b_out[oc1];
    const int tm1 = t - 1;
    #pragma unroll
    for (int r = 0; r < 4; ++r) {
      const int b = wave * 16 + lhi * 4 + r;
      out[((size_t)b * TT + tm1) * OUTP + oc0] = acc0[r] + bo0;
      out[((size_t)b * TT + tm1) * OUTP + oc1] = acc1[r] + bo1;
    }
  }
}

extern "C" void kernel_launch(void* const* d_in, const int* in_sizes, int n_in,
                              void* d_out, int out_size, void* d_ws, size_t ws_size,
                              hipStream_t stream) {
  const float* x     = (const float*)d_in[0];
  const float* W_ih  = (const float*)d_in[1];
  const float* W_hh  = (const float*)d_in[2];
  const float* b_ih  = (const float*)d_in[3];
  const float* b_hh  = (const float*)d_in[4];
  const float* W_out = (const float*)d_in[5];
  const float* b_out = (const float*)d_in[6];
  // d_in[7] = silence_mult: exact identity, h @ I == h bit-exactly -> skipped.
  float* out = (float*)d_out;

  char* ws = (char*)d_ws;
  size_t off = 0;
  half_t* Wp  = (half_t*)(ws + off); off += (size_t)G4 * KK * sizeof(half_t);      // 10.5 MB
  half_t* Wo  = (half_t*)(ws + off); off += (size_t)OUTP * HID * sizeof(half_t);   // 0.5 MB
  half_t* x16 = (half_t*)(ws + off); off += (size_t)BB * TT * INP * sizeof(half_t);// 16.8 MB
  float*  bsum= (float*)(ws + off);  off += (size_t)G4 * sizeof(float);
  half_t* hbuf= (half_t*)(ws + off); off += (size_t)2 * BB * HID * sizeof(half_t);
  float*  cbuf= (float*)(ws + off);  off += (size_t)BB * HID * sizeof(float);

  hipLaunchKernelGGL(setup_kernel, dim3(512), dim3(256), 0, stream,
                     x, W_ih, W_hh, b_ih, b_hh, W_out, Wp, Wo, x16, bsum, hbuf, cbuf);
  for (int t = 0; t <= TT; ++t) {
    hipLaunchKernelGGL(lstm_step, dim3(136), dim3(256), 0, stream,
                       t, Wp, Wo, x16, bsum, b_out, hbuf, cbuf, out);
  }
}

// Round 2
// 8156.973 us; speedup vs baseline: 1.1281x; 1.1281x over previous
//
#include <hip/hip_runtime.h>

#define BB   64
#define TT   512
#define INP  256
#define HID  1024
#define OUTP 256
#define G4   4096
#define KK   1280   // HID + INP
#define NB   136    // 128 gate blocks + 8 out blocks

typedef _Float16 half_t;
typedef __attribute__((ext_vector_type(8))) _Float16 half8;
typedef __attribute__((ext_vector_type(4))) float f32x4;

__device__ __forceinline__ float sigf(float x) { return 1.0f / (1.0f + __expf(-x)); }

// ---------------- setup: convert weights/x to fp16, reset barrier ----------------
__global__ void setup_kernel(const float* __restrict__ x, const float* __restrict__ W_ih,
                             const float* __restrict__ W_hh, const float* __restrict__ b_ih,
                             const float* __restrict__ b_hh, const float* __restrict__ W_out,
                             half_t* __restrict__ Wp, half_t* __restrict__ Wo,
                             half_t* __restrict__ x16, float* __restrict__ bsum,
                             unsigned* __restrict__ cnt) {
  const int stride = gridDim.x * blockDim.x;
  const int i0 = blockIdx.x * blockDim.x + threadIdx.x;
  if (i0 == 0) *cnt = 0u;
  // Wp = [W_hh | W_ih] as (4096, 1280) row-major fp16
  for (int i = i0; i < G4 * KK; i += stride) {
    int n = i / KK, k = i - n * KK;
    float v = (k < HID) ? W_hh[n * HID + k] : W_ih[n * INP + (k - HID)];
    Wp[i] = (half_t)v;
  }
  for (int i = i0; i < OUTP * HID; i += stride) Wo[i] = (half_t)W_out[i];
  for (int i = i0; i < BB * TT * INP; i += stride) x16[i] = (half_t)x[i];
  for (int i = i0; i < G4; i += stride) bsum[i] = b_ih[i] + b_hh[i];
}

// ---------------- grid barrier (monotonic counter, agent scope) ----------------
__device__ __forceinline__ void bar_arrive(unsigned* cnt) {
  __syncthreads();                       // all block stores drained (vmcnt 0 at s_barrier)
  if (threadIdx.x == 0) {
    __builtin_amdgcn_fence(__ATOMIC_RELEASE, "agent");   // writeback XCD L2
    __hip_atomic_fetch_add(cnt, 1u, __ATOMIC_RELAXED, __HIP_MEMORY_SCOPE_AGENT);
  }
}
__device__ __forceinline__ void bar_wait(unsigned* cnt, unsigned target) {
  if (threadIdx.x == 0) {
    while (__hip_atomic_load(cnt, __ATOMIC_RELAXED, __HIP_MEMORY_SCOPE_AGENT) < target)
      __builtin_amdgcn_s_sleep(2);
  }
  __syncthreads();
  __builtin_amdgcn_fence(__ATOMIC_ACQUIRE, "agent");     // invalidate stale L1/L2 lines
}

// ---------------- persistent LSTM ----------------
// blocks 0..127 : gate GEMM + cell update for hidden units [blk*8, blk*8+8)
// blocks 128..135: out[p-2] = h_{p-1} @ W_out^T + b_out
// Phase p (1..512): "h_p published". Every block arrives once per phase 1..512.
__global__ __launch_bounds__(256, 1) void lstm_persist(
    const half_t* __restrict__ Wp,   // (4096, 1280)
    const half_t* __restrict__ Wo,   // (256, 1024)
    const half_t* __restrict__ x16,  // (64, 512, 256)
    const float* __restrict__ bsum,  // (4096)
    const float* __restrict__ b_out, // (256)
    half_t* __restrict__ hbuf,       // 2 x (64, 1024), h_p in slot p&1
    float* __restrict__ out,         // (64, 512, 256)
    unsigned* __restrict__ cnt)
{
  __shared__ half_t lds[32 * 1288];  // 82.4 KB; out blocks use a 32x1032 view
  const int tid  = threadIdx.x;
  const int wave = tid >> 6;
  const int lane = tid & 63;
  const int l15  = lane & 15;
  const int lhi  = lane >> 4;
  const int kbase = lhi * 8;
  const int mrow = wave * 16 + l15;

  if (blockIdx.x < 128) {
    // ================= gate block =================
    const int hu0 = blockIdx.x * 8;
    const int nl0 = l15, nl1 = 16 + l15;
    const int r0 = ((nl0 >> 3) * HID) + hu0 + (nl0 & 7);
    const int r1 = ((nl1 >> 3) * HID) + hu0 + (nl1 & 7);
    // stage this block's 32 gate rows of Wp into LDS (stride 1288 -> 2-way max conflicts)
    for (int v = tid; v < 32 * (KK / 8); v += 256) {
      int nl = v / (KK / 8), kv = (v % (KK / 8)) * 8;
      int rr = ((nl >> 3) * HID) + hu0 + (nl & 7);
      *(half8*)&lds[nl * 1288 + kv] = *(const half8*)&Wp[(size_t)rr * KK + kv];
    }
    __syncthreads();
    const half_t* __restrict__ bp0 = &lds[nl0 * 1288];
    const half_t* __restrict__ bp1 = &lds[nl1 * 1288];
    const float bs0 = bsum[r0], bs1 = bsum[r1];
    float c[4] = {0.f, 0.f, 0.f, 0.f};

    for (int ph = 1; ph <= TT; ++ph) {
      const int t = ph - 1;
      f32x4 acc0 = {0.f, 0.f, 0.f, 0.f}, acc1 = {0.f, 0.f, 0.f, 0.f};
      // ---- x-part (independent of h): overlaps other blocks' tails ----
      const half_t* __restrict__ ax = x16 + ((size_t)mrow * TT + t) * INP;
      #pragma unroll
      for (int kk = 0; kk < INP; kk += 32) {
        half8 a  = *(const half8*)(ax + kk + kbase);
        half8 b0 = *(const half8*)(bp0 + HID + kk + kbase);
        half8 b1 = *(const half8*)(bp1 + HID + kk + kbase);
        acc0 = __builtin_amdgcn_mfma_f32_16x16x32_f16(a, b0, acc0, 0, 0, 0);
        acc1 = __builtin_amdgcn_mfma_f32_16x16x32_f16(a, b1, acc1, 0, 0, 0);
      }
      // ---- h-part (h_0 == 0 -> skipped at ph==1) ----
      if (ph > 1) {
        bar_wait(cnt, (unsigned)(ph - 1) * NB);
        const half_t* __restrict__ ah =
            hbuf + (size_t)((ph - 1) & 1) * (BB * HID) + (size_t)mrow * HID;
        #pragma unroll 8
        for (int kk = 0; kk < HID; kk += 32) {
          half8 a  = *(const half8*)(ah + kk + kbase);
          half8 b0 = *(const half8*)(bp0 + kk + kbase);
          half8 b1 = *(const half8*)(bp1 + kk + kbase);
          acc0 = __builtin_amdgcn_mfma_f32_16x16x32_f16(a, b0, acc0, 0, 0, 0);
          acc1 = __builtin_amdgcn_mfma_f32_16x16x32_f16(a, b1, acc1, 0, 0, 0);
        }
      }
      // ---- cell update; lanes l15<8 hold i (tile0) / g (tile1), partner l^8 holds f / o ----
      float i_or_f[4], g_or_o[4], fsh[4], osh[4];
      #pragma unroll
      for (int r = 0; r < 4; ++r) { i_or_f[r] = acc0[r] + bs0; g_or_o[r] = acc1[r] + bs1; }
      #pragma unroll
      for (int r = 0; r < 4; ++r) {
        fsh[r] = __shfl_xor(i_or_f[r], 8);
        osh[r] = __shfl_xor(g_or_o[r], 8);
      }
      half_t* __restrict__ hnext = hbuf + (size_t)(ph & 1) * (BB * HID);
      if (l15 < 8) {
        const int hu = hu0 + l15;
        #pragma unroll
        for (int r = 0; r < 4; ++r) {
          const int b = wave * 16 + lhi * 4 + r;
          float iv = sigf(i_or_f[r]);
          float fv = sigf(fsh[r]);
          float gv = tanhf(g_or_o[r]);
          float ov = sigf(osh[r]);
          c[r] = fv * c[r] + iv * gv;
          hnext[b * HID + hu] = (half_t)(ov * tanhf(c[r]));
        }
      }
      bar_arrive(cnt);
    }
  } else {
    // ================= out block =================
    const int ob   = blockIdx.x - 128;
    const int base = ob * 32;
    const int oc0  = base + l15, oc1 = base + 16 + l15;
    for (int v = tid; v < 32 * (HID / 8); v += 256) {
      int nl = v / (HID / 8), kv = (v % (HID / 8)) * 8;
      *(half8*)&lds[nl * 1032 + kv] = *(const half8*)&Wo[(size_t)(base + nl) * HID + kv];
    }
    __syncthreads();
    const half_t* __restrict__ bp0 = &lds[l15 * 1032];
    const half_t* __restrict__ bp1 = &lds[(16 + l15) * 1032];
    const float bo0 = b_out[oc0], bo1 = b_out[oc1];
    bar_arrive(cnt);  // participate in phase 1 (no work yet)
    for (int ph = 2; ph <= TT + 1; ++ph) {
      bar_wait(cnt, (unsigned)(ph - 1) * NB);
      const half_t* __restrict__ ah =
          hbuf + (size_t)((ph - 1) & 1) * (BB * HID) + (size_t)mrow * HID;
      f32x4 acc0 = {0.f, 0.f, 0.f, 0.f}, acc1 = {0.f, 0.f, 0.f, 0.f};
      #pragma unroll 8
      for (int kk = 0; kk < HID; kk += 32) {
        half8 a  = *(const half8*)(ah + kk + kbase);
        half8 b0 = *(const half8*)(bp0 + kk + kbase);
        half8 b1 = *(const half8*)(bp1 + kk + kbase);
        acc0 = __builtin_amdgcn_mfma_f32_16x16x32_f16(a, b0, acc0, 0, 0, 0);
        acc1 = __builtin_amdgcn_mfma_f32_16x16x32_f16(a, b1, acc1, 0, 0, 0);
      }
      const int tm1 = ph - 2;
      #pragma unroll
      for (int r = 0; r < 4; ++r) {
        const int b = wave * 16 + lhi * 4 + r;
        out[((size_t)b * TT + tm1) * OUTP + oc0] = acc0[r] + bo0;
        out[((size_t)b * TT + tm1) * OUTP + oc1] = acc1[r] + bo1;
      }
      if (ph <= TT) bar_arrive(cnt);  // last read (h_512) needs no arrival after it
    }
  }
}

extern "C" void kernel_launch(void* const* d_in, const int* in_sizes, int n_in,
                              void* d_out, int out_size, void* d_ws, size_t ws_size,
                              hipStream_t stream) {
  const float* x     = (const float*)d_in[0];
  const float* W_ih  = (const float*)d_in[1];
  const float* W_hh  = (const float*)d_in[2];
  const float* b_ih  = (const float*)d_in[3];
  const float* b_hh  = (const float*)d_in[4];
  const float* W_out = (const float*)d_in[5];
  const float* b_out = (const float*)d_in[6];
  // d_in[7] = silence_mult: exact identity, h @ I == h bit-exactly -> skipped.
  float* out = (float*)d_out;

  char* ws = (char*)d_ws;
  size_t off = 0;
  half_t* Wp  = (half_t*)(ws + off); off += (size_t)G4 * KK * sizeof(half_t);       // 10.5 MB
  half_t* Wo  = (half_t*)(ws + off); off += (size_t)OUTP * HID * sizeof(half_t);    // 0.5 MB
  half_t* x16 = (half_t*)(ws + off); off += (size_t)BB * TT * INP * sizeof(half_t); // 16.8 MB
  float*  bsum= (float*)(ws + off);  off += (size_t)G4 * sizeof(float);
  half_t* hbuf= (half_t*)(ws + off); off += (size_t)2 * BB * HID * sizeof(half_t);
  unsigned* cnt = (unsigned*)(ws + off); off += 64;

  hipLaunchKernelGGL(setup_kernel, dim3(512), dim3(256), 0, stream,
                     x, W_ih, W_hh, b_ih, b_hh, W_out, Wp, Wo, x16, bsum, cnt);
  hipLaunchKernelGGL(lstm_persist, dim3(NB), dim3(256), 0, stream,
                     Wp, Wo, x16, bsum, b_out, hbuf, out, cnt);
}

// Round 3
// 7436.715 us; speedup vs baseline: 1.2373x; 1.0969x over previous
//
#include <hip/hip_runtime.h>

#define BB    64
#define TT    512
#define INP   256
#define HID   1024
#define OUTP  256
#define G4    4096
#define KK    1280   // HID + INP
#define NGATE 128
#define NB    136    // 128 gate blocks + 8 out blocks
#define FSTR  16     // dwords per flag line (64B padding)

typedef _Float16 half_t;
typedef __attribute__((ext_vector_type(8))) _Float16 half8;
typedef __attribute__((ext_vector_type(4))) float f32x4;

__device__ __forceinline__ float sigf(float x) { return 1.0f / (1.0f + __expf(-x)); }

// ---------------- setup: convert weights/x to fp16, zero flags ----------------
__global__ void setup_kernel(const float* __restrict__ x, const float* __restrict__ W_ih,
                             const float* __restrict__ W_hh, const float* __restrict__ b_ih,
                             const float* __restrict__ b_hh, const float* __restrict__ W_out,
                             half_t* __restrict__ Wp, half_t* __restrict__ Wo,
                             half_t* __restrict__ x16, float* __restrict__ bsum,
                             unsigned* __restrict__ flags) {
  const int stride = gridDim.x * blockDim.x;
  const int i0 = blockIdx.x * blockDim.x + threadIdx.x;
  for (int i = i0; i < NB * FSTR; i += stride) flags[i] = 0u;
  // Wp = [W_hh | W_ih] as (4096, 1280) row-major fp16
  for (int i = i0; i < G4 * KK; i += stride) {
    int n = i / KK, k = i - n * KK;
    float v = (k < HID) ? W_hh[n * HID + k] : W_ih[n * INP + (k - HID)];
    Wp[i] = (half_t)v;
  }
  for (int i = i0; i < OUTP * HID; i += stride) Wo[i] = (half_t)W_out[i];
  for (int i = i0; i < BB * TT * INP; i += stride) x16[i] = (half_t)x[i];
  for (int i = i0; i < G4; i += stride) bsum[i] = b_ih[i] + b_hh[i];
}

// ---------------- flag barrier: per-block store + all-see-all poll ----------------
__device__ __forceinline__ void bar_arrive(unsigned* __restrict__ flags, unsigned ph) {
  __syncthreads();  // all block stores drained (vmcnt 0 at s_barrier)
  if (threadIdx.x == 0) {
    __builtin_amdgcn_fence(__ATOMIC_RELEASE, "agent");
    __hip_atomic_store(&flags[blockIdx.x * FSTR], ph, __ATOMIC_RELAXED,
                       __HIP_MEMORY_SCOPE_AGENT);
  }
}
__device__ __forceinline__ void bar_wait(unsigned* __restrict__ flags, unsigned target) {
  if ((threadIdx.x >> 6) == 0) {   // wave 0 polls; others park at the barrier
    const int lane = threadIdx.x & 63;
    for (;;) {
      unsigned v0 = __hip_atomic_load(&flags[lane * FSTR], __ATOMIC_RELAXED,
                                      __HIP_MEMORY_SCOPE_AGENT);
      unsigned v1 = __hip_atomic_load(&flags[(64 + lane) * FSTR], __ATOMIC_RELAXED,
                                      __HIP_MEMORY_SCOPE_AGENT);
      unsigned v2 = __hip_atomic_load(&flags[(128 + (lane & 7)) * FSTR], __ATOMIC_RELAXED,
                                      __HIP_MEMORY_SCOPE_AGENT);
      if (__all(v0 >= target && v1 >= target && v2 >= target)) break;
      __builtin_amdgcn_s_sleep(8);
    }
  }
  __syncthreads();
  __builtin_amdgcn_fence(__ATOMIC_ACQUIRE, "agent");
}

// ---------------- persistent LSTM, weights in VGPRs, K-split across waves ----------------
// blocks 0..127 : 8 hidden units each (32 gate cols x 64 rows), K=1280 split 4 ways
// blocks 128..135: out[p-2] = h_{p-1} @ W_out^T + b_out, K=1024 split 4 ways
__global__ __launch_bounds__(256, 1) void lstm_persist(
    const half_t* __restrict__ Wp,   // (4096, 1280)
    const half_t* __restrict__ Wo,   // (256, 1024)
    const half_t* __restrict__ x16,  // (64, 512, 256)
    const float* __restrict__ bsum,  // (4096)
    const float* __restrict__ b_out, // (256)
    half_t* __restrict__ hbuf,       // 2 x (64, 1024), h_p in slot p&1
    float* __restrict__ out,         // (64, 512, 256)
    unsigned* __restrict__ flags)
{
  __shared__ f32x4 P4[4 * 64 * 8];   // 32KB partial accumulators
  __shared__ float biasg[32];
  const int tid  = threadIdx.x;
  const int wave = tid >> 6;
  const int lane = tid & 63;
  const int l15  = lane & 15;
  const int lhi  = lane >> 4;
  float* Pf = (float*)P4;

  if (blockIdx.x < NGATE) {
    // ================= gate block =================
    const int hu0 = blockIdx.x * 8;
    if (tid < 32) {  // biasg[u*4+g]
      int u = tid >> 2, g = tid & 3;
      biasg[tid] = bsum[g * HID + hu0 + u];
    }
    // B fragments resident in VGPRs: chunks c = wave + 4j, j=0..9 (j>=8 -> x region)
    half8 b[10][2];
    #pragma unroll
    for (int j = 0; j < 10; ++j) {
      const int c = wave + 4 * j;
      #pragma unroll
      for (int n = 0; n < 2; ++n) {
        const int nl = 16 * n + l15;
        const int r  = (nl >> 3) * HID + hu0 + (nl & 7);
        b[j][n] = *(const half8*)&Wp[(size_t)r * KK + 32 * c + 8 * lhi];
      }
    }
    __syncthreads();
    const int rrow = tid >> 2;       // reducer: row 0..63
    const int u0   = 2 * (tid & 3);  // units u0, u0+1
    float cst[2] = {0.f, 0.f};

    for (int ph = 1; ph <= TT; ++ph) {
      const int t = ph - 1;
      f32x4 acc[4][2];
      #pragma unroll
      for (int m = 0; m < 4; ++m)
        #pragma unroll
        for (int n = 0; n < 2; ++n) acc[m][n] = (f32x4){0.f, 0.f, 0.f, 0.f};
      // ---- x chunks (j=8,9): no h dependency, overlap others' tails ----
      #pragma unroll
      for (int j = 8; j < 10; ++j) {
        const int c  = wave + 4 * j;
        const int k0 = 32 * c - HID + 8 * lhi;
        #pragma unroll
        for (int m = 0; m < 4; ++m) {
          half8 a = *(const half8*)&x16[((size_t)(16 * m + l15) * TT + t) * INP + k0];
          #pragma unroll
          for (int n = 0; n < 2; ++n)
            acc[m][n] = __builtin_amdgcn_mfma_f32_16x16x32_f16(a, b[j][n], acc[m][n], 0, 0, 0);
        }
      }
      // ---- h chunks (j=0..7); h_0 == 0 -> skip at ph==1 ----
      if (ph > 1) {
        bar_wait(flags, (unsigned)(ph - 1));
        const half_t* __restrict__ hcur = hbuf + (size_t)((ph - 1) & 1) * (BB * HID);
        #pragma unroll
        for (int j = 0; j < 8; ++j) {
          const int c  = wave + 4 * j;
          const int k0 = 32 * c + 8 * lhi;
          #pragma unroll
          for (int m = 0; m < 4; ++m) {
            half8 a = *(const half8*)&hcur[(size_t)(16 * m + l15) * HID + k0];
            #pragma unroll
            for (int n = 0; n < 2; ++n)
              acc[m][n] = __builtin_amdgcn_mfma_f32_16x16x32_f16(a, b[j][n], acc[m][n], 0, 0, 0);
          }
        }
      }
      // ---- stage partials: P[w][row][slot][gate], slot = (u+row)&7 (bank swizzle) ----
      #pragma unroll
      for (int m = 0; m < 4; ++m)
        #pragma unroll
        for (int n = 0; n < 2; ++n)
          #pragma unroll
          for (int r = 0; r < 4; ++r) {
            const int row  = 16 * m + 4 * lhi + r;
            const int u    = l15 & 7;
            const int g    = 2 * n + (l15 >> 3);
            const int slot = (u + row) & 7;
            Pf[(((wave * 64 + row) * 8 + slot) << 2) + g] = acc[m][n][r];
          }
      __syncthreads();
      // ---- reduce across waves + cell update (c-state in registers) ----
      half_t* __restrict__ hnext = hbuf + (size_t)(ph & 1) * (BB * HID);
      {
        float hv[2];
        #pragma unroll
        for (int uu = 0; uu < 2; ++uu) {
          const int u    = u0 + uu;
          const int slot = (u + rrow) & 7;
          f32x4 s = P4[(0 * 64 + rrow) * 8 + slot];
          #pragma unroll
          for (int w = 1; w < 4; ++w) s += P4[(w * 64 + rrow) * 8 + slot];
          f32x4 bb = *(const f32x4*)&biasg[4 * u];
          float iv = sigf(s[0] + bb[0]);
          float fv = sigf(s[1] + bb[1]);
          float gv = tanhf(s[2] + bb[2]);
          float ov = sigf(s[3] + bb[3]);
          cst[uu] = fv * cst[uu] + iv * gv;
          hv[uu]  = ov * tanhf(cst[uu]);
        }
        union { unsigned u32; half_t h[2]; } pk;
        pk.h[0] = (half_t)hv[0];
        pk.h[1] = (half_t)hv[1];
        *(unsigned*)&hnext[(size_t)rrow * HID + hu0 + u0] = pk.u32;
      }
      bar_arrive(flags, (unsigned)ph);
    }
  } else {
    // ================= out block =================
    const int ob    = blockIdx.x - NGATE;
    const int obase = ob * 32;
    if (tid < 32) biasg[tid] = b_out[obase + tid];
    half8 b[8][2];   // chunks c = wave + 4j, j=0..7 (K=1024)
    #pragma unroll
    for (int j = 0; j < 8; ++j) {
      const int c = wave + 4 * j;
      #pragma unroll
      for (int n = 0; n < 2; ++n) {
        const int col = obase + 16 * n + l15;
        b[j][n] = *(const half8*)&Wo[(size_t)col * HID + 32 * c + 8 * lhi];
      }
    }
    __syncthreads();
    bar_arrive(flags, 1u);   // participate in phase 1 (no work yet)
    const int rrow = tid >> 2;
    const int cg0  = 2 * (tid & 3);
    for (int ph = 2; ph <= TT + 1; ++ph) {
      bar_wait(flags, (unsigned)(ph - 1));
      const half_t* __restrict__ hcur = hbuf + (size_t)((ph - 1) & 1) * (BB * HID);
      f32x4 acc[4][2];
      #pragma unroll
      for (int m = 0; m < 4; ++m)
        #pragma unroll
        for (int n = 0; n < 2; ++n) acc[m][n] = (f32x4){0.f, 0.f, 0.f, 0.f};
      #pragma unroll
      for (int j = 0; j < 8; ++j) {
        const int c  = wave + 4 * j;
        const int k0 = 32 * c + 8 * lhi;
        #pragma unroll
        for (int m = 0; m < 4; ++m) {
          half8 a = *(const half8*)&hcur[(size_t)(16 * m + l15) * HID + k0];
          #pragma unroll
          for (int n = 0; n < 2; ++n)
            acc[m][n] = __builtin_amdgcn_mfma_f32_16x16x32_f16(a, b[j][n], acc[m][n], 0, 0, 0);
        }
      }
      // stage partials: P[w][row][swizzled 32 cols]
      #pragma unroll
      for (int m = 0; m < 4; ++m)
        #pragma unroll
        for (int n = 0; n < 2; ++n)
          #pragma unroll
          for (int r = 0; r < 4; ++r) {
            const int row  = 16 * m + 4 * lhi + r;
            const int col  = 16 * n + l15;
            const int cs   = col >> 2, off = col & 3;
            const int scol = (((cs + row) & 7) << 2) + off;
            Pf[(wave * 64 + row) * 32 + scol] = acc[m][n][r];
          }
      __syncthreads();
      const int tm1 = ph - 2;
      #pragma unroll
      for (int uu = 0; uu < 2; ++uu) {
        const int cg  = cg0 + uu;
        const int scg = (cg + rrow) & 7;
        f32x4 s = P4[(0 * 64 + rrow) * 8 + scg];
        #pragma unroll
        for (int w = 1; w < 4; ++w) s += P4[(w * 64 + rrow) * 8 + scg];
        f32x4 bb = *(const f32x4*)&biasg[4 * cg];
        f32x4 o  = s + bb;
        *(f32x4*)&out[((size_t)rrow * TT + tm1) * OUTP + obase + 4 * cg] = o;
      }
      if (ph <= TT) bar_arrive(flags, (unsigned)ph);
    }
  }
}

extern "C" void kernel_launch(void* const* d_in, const int* in_sizes, int n_in,
                              void* d_out, int out_size, void* d_ws, size_t ws_size,
                              hipStream_t stream) {
  const float* x     = (const float*)d_in[0];
  const float* W_ih  = (const float*)d_in[1];
  const float* W_hh  = (const float*)d_in[2];
  const float* b_ih  = (const float*)d_in[3];
  const float* b_hh  = (const float*)d_in[4];
  const float* W_out = (const float*)d_in[5];
  const float* b_out = (const float*)d_in[6];
  // d_in[7] = silence_mult: exact identity, h @ I == h bit-exactly -> skipped.
  float* out = (float*)d_out;

  char* ws = (char*)d_ws;
  size_t off = 0;
  half_t* Wp  = (half_t*)(ws + off); off += (size_t)G4 * KK * sizeof(half_t);       // 10.5 MB
  half_t* Wo  = (half_t*)(ws + off); off += (size_t)OUTP * HID * sizeof(half_t);    // 0.5 MB
  half_t* x16 = (half_t*)(ws + off); off += (size_t)BB * TT * INP * sizeof(half_t); // 16.8 MB
  float*  bsum= (float*)(ws + off);  off += (size_t)G4 * sizeof(float);
  half_t* hbuf= (half_t*)(ws + off); off += (size_t)2 * BB * HID * sizeof(half_t);
  unsigned* flags = (unsigned*)(ws + off); off += (size_t)NB * FSTR * sizeof(unsigned);

  hipLaunchKernelGGL(setup_kernel, dim3(512), dim3(256), 0, stream,
                     x, W_ih, W_hh, b_ih, b_hh, W_out, Wp, Wo, x16, bsum, flags);
  hipLaunchKernelGGL(lstm_persist, dim3(NB), dim3(256), 0, stream,
                     Wp, Wo, x16, bsum, b_out, hbuf, out, flags);
}

// Round 4
// 6208.178 us; speedup vs baseline: 1.4822x; 1.1979x over previous
//
#include <hip/hip_runtime.h>

#define BB    64
#define TT    512
#define INP   256
#define HID   1024
#define OUTP  256
#define G4    4096
#define KK    1280   // HID + INP
#define NGATE 64
#define NOUT  8
#define NB    72     // 64 gate blocks + 8 out blocks
#define FSTR  16     // dwords per flag line (64B padding)

typedef _Float16 half_t;
typedef __attribute__((ext_vector_type(8))) _Float16 half8;
typedef __attribute__((ext_vector_type(4))) float f32x4;
typedef unsigned long long ull;

union U16 { ull u[2]; half8 v; };

__device__ __forceinline__ float sigf(float x) { return 1.0f / (1.0f + __expf(-x)); }
// MALL-coherent (L1+L2 bypass) accessors — no fences needed anywhere.
__device__ __forceinline__ ull ald(const ull* p) {
  return __hip_atomic_load(p, __ATOMIC_RELAXED, __HIP_MEMORY_SCOPE_AGENT);
}
__device__ __forceinline__ void ast(ull* p, ull v) {
  __hip_atomic_store(p, v, __ATOMIC_RELAXED, __HIP_MEMORY_SCOPE_AGENT);
}
__device__ __forceinline__ unsigned aldu(const unsigned* p) {
  return __hip_atomic_load(p, __ATOMIC_RELAXED, __HIP_MEMORY_SCOPE_AGENT);
}
__device__ __forceinline__ void astu(unsigned* p, unsigned v) {
  __hip_atomic_store(p, v, __ATOMIC_RELAXED, __HIP_MEMORY_SCOPE_AGENT);
}

// ---------------- setup: convert weights/x to fp16, zero flags ----------------
__global__ void setup_kernel(const float* __restrict__ x, const float* __restrict__ W_ih,
                             const float* __restrict__ W_hh, const float* __restrict__ b_ih,
                             const float* __restrict__ b_hh, const float* __restrict__ W_out,
                             half_t* __restrict__ Wp, half_t* __restrict__ Wo,
                             half_t* __restrict__ x16, float* __restrict__ bsum,
                             unsigned* __restrict__ flags) {
  const int stride = gridDim.x * blockDim.x;
  const int i0 = blockIdx.x * blockDim.x + threadIdx.x;
  for (int i = i0; i < NB * FSTR; i += stride) flags[i] = 0u;
  // Wp = [W_hh | W_ih] as (4096, 1280) row-major fp16
  for (int i = i0; i < G4 * KK; i += stride) {
    int n = i / KK, k = i - n * KK;
    float v = (k < HID) ? W_hh[n * HID + k] : W_ih[n * INP + (k - HID)];
    Wp[i] = (half_t)v;
  }
  for (int i = i0; i < OUTP * HID; i += stride) Wo[i] = (half_t)W_out[i];
  for (int i = i0; i < BB * TT * INP; i += stride) x16[i] = (half_t)x[i];
  for (int i = i0; i < G4; i += stride) bsum[i] = b_ih[i] + b_hh[i];
}

// ---------------- fence-free flag barrier ----------------
__device__ __forceinline__ void bar_arrive(unsigned* __restrict__ flags, unsigned ph) {
  __syncthreads();  // all waves' h-stores (vmcnt) drained before the flag goes out
  if (threadIdx.x == 0) astu(&flags[blockIdx.x * FSTR], ph);
}
__device__ __forceinline__ void bar_wait(unsigned* __restrict__ flags, unsigned target) {
  if ((threadIdx.x >> 6) == 0) {   // wave 0 polls; others park at the barrier
    const int lane = threadIdx.x & 63;
    for (;;) {
      unsigned v0 = aldu(&flags[lane * FSTR]);
      unsigned v1 = (lane < NOUT) ? aldu(&flags[(64 + lane) * FSTR]) : 0xFFFFFFFFu;
      if (__all(v0 >= target && v1 >= target)) break;
      __builtin_amdgcn_s_sleep(1);
    }
  }
  __syncthreads();
}

// ---------------- persistent LSTM ----------------
// blocks 0..63 : 16 hidden units each (64 gate cols = 4 gates x 16 units), K split 4 waves
// blocks 64..71: out[p-2] = h_{p-1} @ W_out^T + b_out (32 cols each)
__global__ __launch_bounds__(256, 1) void lstm_persist(
    const half_t* __restrict__ Wp,   // (4096, 1280)
    const half_t* __restrict__ Wo,   // (256, 1024)
    const half_t* __restrict__ x16,  // (64, 512, 256)
    const float* __restrict__ bsum,  // (4096)
    const float* __restrict__ b_out, // (256)
    half_t* __restrict__ hbuf,       // 2 x (64, 1024), h_p in slot p&1 (MALL-only data)
    float* __restrict__ out,         // (64, 512, 256)
    unsigned* __restrict__ flags)
{
  __shared__ float Pf[4 * 64 * 68];  // 69.6 KB partials (row stride 68 dwords)
  __shared__ float biasg[64];
  f32x4* P4 = (f32x4*)Pf;
  const int tid  = threadIdx.x;
  const int wave = tid >> 6;
  const int lane = tid & 63;
  const int l15  = lane & 15;
  const int lhi  = lane >> 4;

  if (blockIdx.x < NGATE) {
    // ================= gate block =================
    const int u0 = blockIdx.x * 16;
    if (tid < 64) biasg[tid] = bsum[(tid & 3) * HID + u0 + (tid >> 2)];  // [uu][g]
    // weights in VGPRs: chunk c = wave + 4*jj (jj 0..9; jj>=8 -> x region), g = n-tile = gate
    half8 b[10][4];
    #pragma unroll
    for (int jj = 0; jj < 10; ++jj) {
      const int c = wave + 4 * jj;
      #pragma unroll
      for (int g = 0; g < 4; ++g) {
        const int r = g * HID + u0 + l15;
        b[jj][g] = *(const half8*)&Wp[(size_t)r * KK + 32 * c + 8 * lhi];
      }
    }
    __syncthreads();
    const int rrow = tid >> 2;       // reducer: row 0..63
    const int ug   = (tid & 3) * 4;  // units ug..ug+3
    float cst[4] = {0.f, 0.f, 0.f, 0.f};

    for (int ph = 1; ph <= TT; ++ph) {
      const int t = ph - 1;
      f32x4 acc[4][4];
      #pragma unroll
      for (int m = 0; m < 4; ++m)
        #pragma unroll
        for (int g = 0; g < 4; ++g) acc[m][g] = (f32x4){0.f, 0.f, 0.f, 0.f};
      // ---- x part (no h dependency; plain loads, L2-cached) ----
      #pragma unroll
      for (int jx = 0; jx < 2; ++jx) {
        const int kx = 32 * (wave + 4 * jx) + 8 * lhi;   // x-region k offset
        #pragma unroll
        for (int m = 0; m < 4; ++m) {
          half8 a = *(const half8*)&x16[((size_t)(16 * m + l15) * TT + t) * INP + kx];
          #pragma unroll
          for (int g = 0; g < 4; ++g)
            acc[m][g] = __builtin_amdgcn_mfma_f32_16x16x32_f16(a, b[8 + jx][g], acc[m][g], 0, 0, 0);
        }
      }
      // ---- h part: MALL-coherent b64 loads, all issued before use ----
      if (ph > 1) {
        bar_wait(flags, (unsigned)(ph - 1));
        const half_t* __restrict__ hcur = hbuf + (size_t)((ph - 1) & 1) * (BB * HID);
        U16 ahA[4][4], ahB[4][4];
        #pragma unroll
        for (int jj = 0; jj < 4; ++jj) {
          const int k0 = 32 * (wave + 4 * jj) + 8 * lhi;
          #pragma unroll
          for (int m = 0; m < 4; ++m) {
            const ull* p = (const ull*)&hcur[(size_t)(16 * m + l15) * HID + k0];
            ahA[jj][m].u[0] = ald(p);
            ahA[jj][m].u[1] = ald(p + 1);
          }
        }
        #pragma unroll
        for (int jj = 4; jj < 8; ++jj) {
          const int k0 = 32 * (wave + 4 * jj) + 8 * lhi;
          #pragma unroll
          for (int m = 0; m < 4; ++m) {
            const ull* p = (const ull*)&hcur[(size_t)(16 * m + l15) * HID + k0];
            ahB[jj - 4][m].u[0] = ald(p);
            ahB[jj - 4][m].u[1] = ald(p + 1);
          }
        }
        #pragma unroll
        for (int jj = 0; jj < 4; ++jj)
          #pragma unroll
          for (int m = 0; m < 4; ++m)
            #pragma unroll
            for (int g = 0; g < 4; ++g)
              acc[m][g] = __builtin_amdgcn_mfma_f32_16x16x32_f16(ahA[jj][m].v, b[jj][g], acc[m][g], 0, 0, 0);
        #pragma unroll
        for (int jj = 4; jj < 8; ++jj)
          #pragma unroll
          for (int m = 0; m < 4; ++m)
            #pragma unroll
            for (int g = 0; g < 4; ++g)
              acc[m][g] = __builtin_amdgcn_mfma_f32_16x16x32_f16(ahB[jj - 4][m].v, b[jj][g], acc[m][g], 0, 0, 0);
      }
      // ---- stage partials: dword (w*64+row)*68 + slot*4 + g, slot = (unit+row)&15 ----
      #pragma unroll
      for (int m = 0; m < 4; ++m)
        #pragma unroll
        for (int g = 0; g < 4; ++g)
          #pragma unroll
          for (int r = 0; r < 4; ++r) {
            const int row  = 16 * m + 4 * lhi + r;
            const int slot = (l15 + row) & 15;
            Pf[(wave * 64 + row) * 68 + slot * 4 + g] = acc[m][g][r];
          }
      __syncthreads();
      // ---- reduce + cell update; c-state in registers ----
      half_t* __restrict__ hnext = hbuf + (size_t)(ph & 1) * (BB * HID);
      {
        half_t hv[4];
        #pragma unroll
        for (int uu = 0; uu < 4; ++uu) {
          const int u    = ug + uu;
          const int slot = (u + rrow) & 15;
          f32x4 s = *(const f32x4*)&Pf[(0 * 64 + rrow) * 68 + slot * 4];
          #pragma unroll
          for (int w = 1; w < 4; ++w) s += *(const f32x4*)&Pf[(w * 64 + rrow) * 68 + slot * 4];
          f32x4 bb = *(const f32x4*)&biasg[4 * u];
          float iv = sigf(s[0] + bb[0]);
          float fv = sigf(s[1] + bb[1]);
          float gv = tanhf(s[2] + bb[2]);
          float ov = sigf(s[3] + bb[3]);
          cst[uu] = fv * cst[uu] + iv * gv;
          hv[uu]  = (half_t)(ov * tanhf(cst[uu]));
        }
        union { ull u64; half_t h[4]; } pk;
        pk.h[0] = hv[0]; pk.h[1] = hv[1]; pk.h[2] = hv[2]; pk.h[3] = hv[3];
        ast((ull*)&hnext[(size_t)rrow * HID + u0 + ug], pk.u64);
      }
      bar_arrive(flags, (unsigned)ph);
    }
  } else {
    // ================= out block =================
    const int ob    = blockIdx.x - NGATE;
    const int obase = ob * 32;
    if (tid < 32) biasg[tid] = b_out[obase + tid];
    half8 b[8][2];   // chunks c = wave + 4j, j=0..7 (K=1024)
    #pragma unroll
    for (int j = 0; j < 8; ++j) {
      const int c = wave + 4 * j;
      #pragma unroll
      for (int n = 0; n < 2; ++n) {
        const int col = obase + 16 * n + l15;
        b[j][n] = *(const half8*)&Wo[(size_t)col * HID + 32 * c + 8 * lhi];
      }
    }
    __syncthreads();
    bar_arrive(flags, 1u);   // participate in phase 1 (no work yet)
    const int rrow = tid >> 2;
    const int cg0  = 2 * (tid & 3);
    for (int ph = 2; ph <= TT + 1; ++ph) {
      bar_wait(flags, (unsigned)(ph - 1));
      const half_t* __restrict__ hcur = hbuf + (size_t)((ph - 1) & 1) * (BB * HID);
      U16 ahA[4][4], ahB[4][4];
      #pragma unroll
      for (int j = 0; j < 4; ++j) {
        const int k0 = 32 * (wave + 4 * j) + 8 * lhi;
        #pragma unroll
        for (int m = 0; m < 4; ++m) {
          const ull* p = (const ull*)&hcur[(size_t)(16 * m + l15) * HID + k0];
          ahA[j][m].u[0] = ald(p);
          ahA[j][m].u[1] = ald(p + 1);
        }
      }
      #pragma unroll
      for (int j = 4; j < 8; ++j) {
        const int k0 = 32 * (wave + 4 * j) + 8 * lhi;
        #pragma unroll
        for (int m = 0; m < 4; ++m) {
          const ull* p = (const ull*)&hcur[(size_t)(16 * m + l15) * HID + k0];
          ahB[j - 4][m].u[0] = ald(p);
          ahB[j - 4][m].u[1] = ald(p + 1);
        }
      }
      f32x4 acc[4][2];
      #pragma unroll
      for (int m = 0; m < 4; ++m)
        #pragma unroll
        for (int n = 0; n < 2; ++n) acc[m][n] = (f32x4){0.f, 0.f, 0.f, 0.f};
      #pragma unroll
      for (int j = 0; j < 4; ++j)
        #pragma unroll
        for (int m = 0; m < 4; ++m)
          #pragma unroll
          for (int n = 0; n < 2; ++n)
            acc[m][n] = __builtin_amdgcn_mfma_f32_16x16x32_f16(ahA[j][m].v, b[j][n], acc[m][n], 0, 0, 0);
      #pragma unroll
      for (int j = 4; j < 8; ++j)
        #pragma unroll
        for (int m = 0; m < 4; ++m)
          #pragma unroll
          for (int n = 0; n < 2; ++n)
            acc[m][n] = __builtin_amdgcn_mfma_f32_16x16x32_f16(ahB[j - 4][m].v, b[j][n], acc[m][n], 0, 0, 0);
      // stage partials: Pf[(w*64+row)*32 + scol], scol swizzled
      #pragma unroll
      for (int m = 0; m < 4; ++m)
        #pragma unroll
        for (int n = 0; n < 2; ++n)
          #pragma unroll
          for (int r = 0; r < 4; ++r) {
            const int row  = 16 * m + 4 * lhi + r;
            const int col  = 16 * n + l15;
            const int cs   = col >> 2, off = col & 3;
            const int scol = (((cs + row) & 7) << 2) + off;
            Pf[(wave * 64 + row) * 32 + scol] = acc[m][n][r];
          }
      __syncthreads();
      const int tm1 = ph - 2;
      #pragma unroll
      for (int uu = 0; uu < 2; ++uu) {
        const int cg  = cg0 + uu;
        const int scg = (cg + rrow) & 7;
        f32x4 s = P4[(0 * 64 + rrow) * 8 + scg];
        #pragma unroll
        for (int w = 1; w < 4; ++w) s += P4[(w * 64 + rrow) * 8 + scg];
        f32x4 bb = *(const f32x4*)&biasg[4 * cg];
        f32x4 o  = s + bb;
        *(f32x4*)&out[((size_t)rrow * TT + tm1) * OUTP + obase + 4 * cg] = o;
      }
      if (ph <= TT) bar_arrive(flags, (unsigned)ph);
      else __syncthreads();  // keep wave0 poll state consistent on last iter
    }
  }
}

extern "C" void kernel_launch(void* const* d_in, const int* in_sizes, int n_in,
                              void* d_out, int out_size, void* d_ws, size_t ws_size,
                              hipStream_t stream) {
  const float* x     = (const float*)d_in[0];
  const float* W_ih  = (const float*)d_in[1];
  const float* W_hh  = (const float*)d_in[2];
  const float* b_ih  = (const float*)d_in[3];
  const float* b_hh  = (const float*)d_in[4];
  const float* W_out = (const float*)d_in[5];
  const float* b_out = (const float*)d_in[6];
  // d_in[7] = silence_mult: exact identity, h @ I == h bit-exactly -> skipped.
  float* out = (float*)d_out;

  char* ws = (char*)d_ws;
  size_t off = 0;
  half_t* Wp  = (half_t*)(ws + off); off += (size_t)G4 * KK * sizeof(half_t);       // 10.5 MB
  half_t* Wo  = (half_t*)(ws + off); off += (size_t)OUTP * HID * sizeof(half_t);    // 0.5 MB
  half_t* x16 = (half_t*)(ws + off); off += (size_t)BB * TT * INP * sizeof(half_t); // 16.8 MB
  float*  bsum= (float*)(ws + off);  off += (size_t)G4 * sizeof(float);
  half_t* hbuf= (half_t*)(ws + off); off += (size_t)2 * BB * HID * sizeof(half_t);
  unsigned* flags = (unsigned*)(ws + off); off += (size_t)NB * FSTR * sizeof(unsigned);

  hipLaunchKernelGGL(setup_kernel, dim3(512), dim3(256), 0, stream,
                     x, W_ih, W_hh, b_ih, b_hh, W_out, Wp, Wo, x16, bsum, flags);
  hipLaunchKernelGGL(lstm_persist, dim3(NB), dim3(256), 0, stream,
                     Wp, Wo, x16, bsum, b_out, hbuf, out, flags);
}